// Round 1
// baseline (790.416 us; speedup 1.0000x reference)
//
#include <hip/hip_runtime.h>

// Problem constants (G=8, T=4096, H=2048, E=64, k=2)
#define NG 8
#define NT 4096
#define NH 2048
#define NE 64
#define NTOK (NG * NT)   // 32768

// Output layout (all float32 in d_out):
//   [0, 131072)          dispatch_indices [8,4096,2,2]
//   [131072, 196608)     combine_weights  [8,4096,2]
//   [196608]             auxiliary_loss
//   [196609, 2293761)    router_probs     [8,4096,64]
//   [2293761]            router_z_loss

// ---------------- GEMM: logits = A @ W  (bias added in epilogue) --------------
__global__ __launch_bounds__(256) void kgemm(const float* __restrict__ A,
                                             const float* __restrict__ W,
                                             const float* __restrict__ bias,
                                             float* __restrict__ out /*logits*/) {
    __shared__ float As[64][68];   // [k][token], +4 pad keeps float4 alignment
    __shared__ float Ws[64][64];   // [k][expert]
    const int tid = threadIdx.x;
    const size_t tBase = (size_t)blockIdx.x * 64;
    const int tg = tid & 15, eg = tid >> 4;   // compute mapping: 4 tokens x 4 experts
    const int tx = tid & 15, ty = tid >> 4;   // staging mapping

    float acc[4][4];
#pragma unroll
    for (int i = 0; i < 4; ++i)
#pragma unroll
        for (int j = 0; j < 4; ++j) acc[i][j] = 0.0f;

    float4 ar[4], wr[4];
    // prologue: load chunk 0
#pragma unroll
    for (int p = 0; p < 4; ++p) {
        ar[p] = *(const float4*)(A + (tBase + ty + 16 * p) * (size_t)NH + 4 * tx);
        wr[p] = *(const float4*)(W + (size_t)(ty + 16 * p) * NE + 4 * tx);
    }

    for (int kc = 0; kc < NH; kc += 64) {
        __syncthreads();   // LDS free from previous compute
#pragma unroll
        for (int p = 0; p < 4; ++p) {
            As[4 * tx + 0][ty + 16 * p] = ar[p].x;
            As[4 * tx + 1][ty + 16 * p] = ar[p].y;
            As[4 * tx + 2][ty + 16 * p] = ar[p].z;
            As[4 * tx + 3][ty + 16 * p] = ar[p].w;
            *(float4*)&Ws[ty + 16 * p][4 * tx] = wr[p];
        }
        __syncthreads();
        if (kc + 64 < NH) {   // prefetch next chunk while computing this one
#pragma unroll
            for (int p = 0; p < 4; ++p) {
                ar[p] = *(const float4*)(A + (tBase + ty + 16 * p) * (size_t)NH + (kc + 64) + 4 * tx);
                wr[p] = *(const float4*)(W + (size_t)(kc + 64 + ty + 16 * p) * NE + 4 * tx);
            }
        }
#pragma unroll 8
        for (int k = 0; k < 64; ++k) {
            const float4 av = *(const float4*)&As[k][4 * tg];
            const float4 wv = *(const float4*)&Ws[k][4 * eg];
            const float a4[4] = {av.x, av.y, av.z, av.w};
            const float w4[4] = {wv.x, wv.y, wv.z, wv.w};
#pragma unroll
            for (int i = 0; i < 4; ++i)
#pragma unroll
                for (int j = 0; j < 4; ++j) acc[i][j] += a4[i] * w4[j];
        }
    }

    // epilogue: scalar stores (out region is only 4B-aligned)
#pragma unroll
    for (int i = 0; i < 4; ++i) {
        const size_t tok = tBase + 4 * tg + i;
#pragma unroll
        for (int j = 0; j < 4; ++j) {
            const int e = 4 * eg + j;
            out[tok * NE + e] = acc[i][j] + bias[e];
        }
    }
}

// ------------- softmax + top2 + z-loss partial + expert counts ---------------
__global__ __launch_bounds__(256) void ksoftmax(float* __restrict__ probs,  // in logits, out probs
                                                float* __restrict__ g0, float* __restrict__ g1,
                                                int* __restrict__ i0, int* __restrict__ i1,
                                                int* __restrict__ gcnt, float* __restrict__ zacc) {
    const int t = blockIdx.x * 256 + threadIdx.x;
    const int g = t >> 12;
    float* row = probs + (size_t)t * NE;
    float l[NE];
#pragma unroll
    for (int i = 0; i < NE; ++i) l[i] = row[i];
    float m = l[0];
#pragma unroll
    for (int i = 1; i < NE; ++i) m = fmaxf(m, l[i]);
    float s = 0.0f;
#pragma unroll
    for (int i = 0; i < NE; ++i) { l[i] = expf(l[i] - m); s += l[i]; }
    const float lse = m + logf(s);

    float p1 = -1.0f, p2 = -1.0f;
    int e1 = 0, e2 = 0;
#pragma unroll
    for (int i = 0; i < NE; ++i) {
        const float p = l[i] / s;   // match reference: exp / sum
        row[i] = p;
        if (p > p1) { p2 = p1; e2 = e1; p1 = p; e1 = i; }
        else if (p > p2) { p2 = p; e2 = i; }
    }
    g0[t] = p1; g1[t] = p2; i0[t] = e1; i1[t] = e2;

    __shared__ int cnt[NE];
    __shared__ float red[256];
    if (threadIdx.x < NE) cnt[threadIdx.x] = 0;
    __syncthreads();
    atomicAdd(&cnt[e1], 1);
    atomicAdd(&cnt[e2], 1);
    red[threadIdx.x] = lse * lse;
    __syncthreads();
    for (int st = 128; st > 0; st >>= 1) {
        if (threadIdx.x < st) red[threadIdx.x] += red[threadIdx.x + st];
        __syncthreads();
    }
    if (threadIdx.x == 0) atomicAdd(zacc, red[0]);
    if (threadIdx.x < NE) atomicAdd(&gcnt[(g << 6) + threadIdx.x], cnt[threadIdx.x]);
}

// ------------------------ per-(g,e) prob column sums -------------------------
__global__ __launch_bounds__(256) void kpsum(const float* __restrict__ probs,
                                             float* __restrict__ psum) {
    const int g = blockIdx.x, tid = threadIdx.x;
    const int e = tid & 63, r = tid >> 6;
    const float* pg = probs + ((size_t)g << 12) * NE;
    float acc = 0.0f;
    for (int t = r; t < NT; t += 4) acc += pg[(size_t)t * NE + e];
    __shared__ float red[256];
    red[tid] = acc;
    __syncthreads();
    if (tid < 64) psum[(g << 6) + e] = red[e] + red[64 + e] + red[128 + e] + red[192 + e];
}

// ----------- per-group: stable sort by top1 prob, rank, emit outputs ---------
__global__ __launch_bounds__(1024) void krouter(const float* __restrict__ g0,
                                                const float* __restrict__ g1,
                                                const int* __restrict__ i0,
                                                const int* __restrict__ i1,
                                                const int* __restrict__ capPtr,
                                                float* __restrict__ outDisp,
                                                float* __restrict__ outComb) {
    const int g = blockIdx.x, tid = threadIdx.x;
    __shared__ unsigned long long sk[NT];            // 32 KB sort keys
    __shared__ __align__(16) unsigned char seq[2 * NT];  // 8 KB expert sequence
    __shared__ unsigned short rank[2 * NT];          // 16 KB local ranks
    __shared__ int hist[16][64];                     // 4 KB chunk histograms

    const float* g0g = g0 + (g << 12);
    const float* g1g = g1 + (g << 12);
    const int* i0g = i0 + (g << 12);
    const int* i1g = i1 + (g << 12);

    // keys: descending top1-prob, ties -> ascending token (== stable argsort(-gate))
    for (int s = tid; s < NT; s += 1024) {
        const unsigned int pb = __float_as_uint(g0g[s]);   // prob > 0 -> orderable bits
        sk[s] = ((unsigned long long)(~pb) << 32) | (unsigned int)s;
    }
    __syncthreads();

    // bitonic sort ascending, n = 4096
    for (int k = 2; k <= NT; k <<= 1) {
        for (int j = k >> 1; j > 0; j >>= 1) {
            for (int i = tid; i < NT; i += 1024) {
                const int l = i ^ j;
                if (l > i) {
                    const unsigned long long a = sk[i], b = sk[l];
                    const bool up = ((i & k) == 0);
                    if ((a > b) == up) { sk[i] = b; sk[l] = a; }
                }
            }
            __syncthreads();
        }
    }

    // expert sequence: slot0 of sorted tokens, then slot1
    for (int s = tid; s < NT; s += 1024) {
        const int tok = (int)(sk[s] & 0xFFFFu);
        seq[s] = (unsigned char)i0g[tok];
        seq[NT + s] = (unsigned char)i1g[tok];
    }
    __syncthreads();

    // chunked per-expert running rank: 16 waves x 512 items, lane == expert
    const int wave = tid >> 6, lane = tid & 63;
    const int base = wave << 9;
    int cnt = 0;
    const unsigned long long* sp8 = (const unsigned long long*)(seq + base);
    for (int i = 0; i < 64; ++i) {
        const unsigned long long v = sp8[i];
#pragma unroll
        for (int b = 0; b < 8; ++b) {
            const int ex = (int)((v >> (8 * b)) & 0xFFu);
            const bool mt = (ex == lane);
            if (mt) rank[base + i * 8 + b] = (unsigned short)cnt;
            cnt += mt ? 1 : 0;
        }
    }
    hist[wave][lane] = cnt;
    __syncthreads();
    if (tid < 64) {   // exclusive scan over chunks per expert
        int off = 0;
#pragma unroll
        for (int w = 0; w < 16; ++w) { const int c = hist[w][tid]; hist[w][tid] = off; off += c; }
    }
    __syncthreads();

    const int cap = capPtr[0];
    for (int s = tid; s < 2 * NT; s += 1024) {
        const int slot = s >> 12;
        const int sp = s & (NT - 1);
        const int tok = (int)(sk[sp] & 0xFFFFu);
        const int e = seq[s];
        const int pri = (int)rank[s] + hist[s >> 9][e];
        const float gate = slot ? g1g[tok] : g0g[tok];
        const float cw = (pri < cap) ? gate : 0.0f;
        const size_t ob = (((size_t)(g << 12) + tok) * 2 + slot) * 2;
        outDisp[ob] = (float)e;
        outDisp[ob + 1] = (float)pri;
        outComb[((size_t)(g << 12) + tok) * 2 + slot] = cw;
    }
}

// ------------------------------ scalar losses --------------------------------
__global__ __launch_bounds__(512) void kfinal(const int* __restrict__ gcnt,
                                              const float* __restrict__ psum,
                                              const float* __restrict__ zacc,
                                              float* __restrict__ outAux,
                                              float* __restrict__ outZ) {
    __shared__ float red[512];
    const int tid = threadIdx.x;
    red[tid] = (float)gcnt[tid] * psum[tid];
    __syncthreads();
    for (int st = 256; st > 0; st >>= 1) {
        if (tid < st) red[tid] += red[tid + st];
        __syncthreads();
    }
    if (tid == 0) {
        *outAux = red[0] * ((float)NE / ((float)NG * (float)NT * (float)NT));
        *outZ = zacc[0] * (1.0f / (float)NTOK);
    }
}

extern "C" void kernel_launch(void* const* d_in, const int* in_sizes, int n_in,
                              void* d_out, int out_size, void* d_ws, size_t ws_size,
                              hipStream_t stream) {
    const float* A = (const float*)d_in[0];
    const float* W = (const float*)d_in[1];
    const float* bias = (const float*)d_in[2];
    const int* cap = (const int*)d_in[3];

    float* out = (float*)d_out;
    float* outDisp = out;                    // 131072
    float* outComb = out + 131072;           // 65536
    float* outAux = out + 196608;            // 1
    float* probs = out + 196609;             // 2097152 (logits then probs)
    float* outZ = out + 2293761;             // 1

    float* wsf = (float*)d_ws;
    int* gcnt = (int*)d_ws;                  // 512 ints
    float* psum = wsf + 512;                 // 512 floats
    float* zacc = wsf + 1024;                // 1 float
    float* g0 = wsf + 1088;                  // 32768
    float* g1 = wsf + 1088 + 32768;          // 32768
    int* i0 = (int*)d_ws + 1088 + 65536;     // 32768
    int* i1 = (int*)d_ws + 1088 + 98304;     // 32768

    hipMemsetAsync(d_ws, 0, 4100, stream);   // zero gcnt, psum, zacc

    kgemm<<<NTOK / 64, 256, 0, stream>>>(A, W, bias, probs);
    ksoftmax<<<NTOK / 256, 256, 0, stream>>>(probs, g0, g1, i0, i1, gcnt, zacc);
    kpsum<<<NG, 256, 0, stream>>>(probs, psum);
    krouter<<<NG, 1024, 0, stream>>>(g0, g1, i0, i1, cap, outDisp, outComb);
    kfinal<<<1, 512, 0, stream>>>(gcnt, psum, zacc, outAux, outZ);
}

// Round 2
// 560.175 us; speedup vs baseline: 1.4110x; 1.4110x over previous
//
#include <hip/hip_runtime.h>

// Problem constants (G=8, T=4096, H=2048, E=64, k=2)
#define NG 8
#define NT 4096
#define NH 2048
#define NE 64
#define NTOK (NG * NT)   // 32768

// Output layout (all float32 in d_out):
//   [0, 131072)          dispatch_indices [8,4096,2,2]
//   [131072, 196608)     combine_weights  [8,4096,2]
//   [196608]             auxiliary_loss
//   [196609, 2293761)    router_probs     [8,4096,64]
//   [2293761]            router_z_loss

// ---------------- GEMM: logits = A @ W  (bias added in epilogue) --------------
__global__ __launch_bounds__(256) void kgemm(const float* __restrict__ A,
                                             const float* __restrict__ W,
                                             const float* __restrict__ bias,
                                             float* __restrict__ out /*logits*/) {
    __shared__ float As[64][68];   // [k][token], +4 pad keeps float4 alignment
    __shared__ float Ws[64][64];   // [k][expert]
    const int tid = threadIdx.x;
    const size_t tBase = (size_t)blockIdx.x * 64;
    const int tg = tid & 15, eg = tid >> 4;   // compute mapping: 4 tokens x 4 experts
    const int tx = tid & 15, ty = tid >> 4;   // staging mapping

    float acc[4][4];
#pragma unroll
    for (int i = 0; i < 4; ++i)
#pragma unroll
        for (int j = 0; j < 4; ++j) acc[i][j] = 0.0f;

    float4 ar[4], wr[4];
    // prologue: load chunk 0
#pragma unroll
    for (int p = 0; p < 4; ++p) {
        ar[p] = *(const float4*)(A + (tBase + ty + 16 * p) * (size_t)NH + 4 * tx);
        wr[p] = *(const float4*)(W + (size_t)(ty + 16 * p) * NE + 4 * tx);
    }

    for (int kc = 0; kc < NH; kc += 64) {
        __syncthreads();   // LDS free from previous compute
#pragma unroll
        for (int p = 0; p < 4; ++p) {
            As[4 * tx + 0][ty + 16 * p] = ar[p].x;
            As[4 * tx + 1][ty + 16 * p] = ar[p].y;
            As[4 * tx + 2][ty + 16 * p] = ar[p].z;
            As[4 * tx + 3][ty + 16 * p] = ar[p].w;
            *(float4*)&Ws[ty + 16 * p][4 * tx] = wr[p];
        }
        __syncthreads();
        if (kc + 64 < NH) {   // prefetch next chunk while computing this one
#pragma unroll
            for (int p = 0; p < 4; ++p) {
                ar[p] = *(const float4*)(A + (tBase + ty + 16 * p) * (size_t)NH + (kc + 64) + 4 * tx);
                wr[p] = *(const float4*)(W + (size_t)(kc + 64 + ty + 16 * p) * NE + 4 * tx);
            }
        }
#pragma unroll 8
        for (int k = 0; k < 64; ++k) {
            const float4 av = *(const float4*)&As[k][4 * tg];
            const float4 wv = *(const float4*)&Ws[k][4 * eg];
            const float a4[4] = {av.x, av.y, av.z, av.w};
            const float w4[4] = {wv.x, wv.y, wv.z, wv.w};
#pragma unroll
            for (int i = 0; i < 4; ++i)
#pragma unroll
                for (int j = 0; j < 4; ++j) acc[i][j] += a4[i] * w4[j];
        }
    }

    // epilogue: scalar stores (out region is only 4B-aligned)
#pragma unroll
    for (int i = 0; i < 4; ++i) {
        const size_t tok = tBase + 4 * tg + i;
#pragma unroll
        for (int j = 0; j < 4; ++j) {
            const int e = 4 * eg + j;
            out[tok * NE + e] = acc[i][j] + bias[e];
        }
    }
}

// ------------- softmax + top2 + z-loss partial + expert counts ---------------
__global__ __launch_bounds__(256) void ksoftmax(float* __restrict__ probs,  // in logits, out probs
                                                float* __restrict__ g0, float* __restrict__ g1,
                                                int* __restrict__ i0, int* __restrict__ i1,
                                                int* __restrict__ gcnt, float* __restrict__ zacc) {
    const int t = blockIdx.x * 256 + threadIdx.x;
    const int g = t >> 12;
    float* row = probs + (size_t)t * NE;
    float l[NE];
#pragma unroll
    for (int i = 0; i < NE; ++i) l[i] = row[i];
    float m = l[0];
#pragma unroll
    for (int i = 1; i < NE; ++i) m = fmaxf(m, l[i]);
    float s = 0.0f;
#pragma unroll
    for (int i = 0; i < NE; ++i) { l[i] = expf(l[i] - m); s += l[i]; }
    const float lse = m + logf(s);

    float p1 = -1.0f, p2 = -1.0f;
    int e1 = 0, e2 = 0;
#pragma unroll
    for (int i = 0; i < NE; ++i) {
        const float p = l[i] / s;   // match reference: exp / sum
        row[i] = p;
        if (p > p1) { p2 = p1; e2 = e1; p1 = p; e1 = i; }
        else if (p > p2) { p2 = p; e2 = i; }
    }
    g0[t] = p1; g1[t] = p2; i0[t] = e1; i1[t] = e2;

    __shared__ int cnt[NE];
    __shared__ float red[256];
    if (threadIdx.x < NE) cnt[threadIdx.x] = 0;
    __syncthreads();
    atomicAdd(&cnt[e1], 1);
    atomicAdd(&cnt[e2], 1);
    red[threadIdx.x] = lse * lse;
    __syncthreads();
    for (int st = 128; st > 0; st >>= 1) {
        if (threadIdx.x < st) red[threadIdx.x] += red[threadIdx.x + st];
        __syncthreads();
    }
    if (threadIdx.x == 0) atomicAdd(zacc, red[0]);
    if (threadIdx.x < NE) atomicAdd(&gcnt[(g << 6) + threadIdx.x], cnt[threadIdx.x]);
}

// ------------- per-(g,e) prob column sums: 64 slices per group ---------------
__global__ __launch_bounds__(256) void kpsum(const float* __restrict__ probs,
                                             float* __restrict__ psum) {
    const int g = blockIdx.x >> 6, slice = blockIdx.x & 63;
    const int tid = threadIdx.x;
    const int e = tid & 63, r = tid >> 6;
    const float* pg = probs + (((size_t)g << 12) + ((size_t)slice << 6)) * NE;
    float acc = 0.0f;
#pragma unroll
    for (int t = r; t < 64; t += 4) acc += pg[(size_t)t * NE + e];
    __shared__ float red[256];
    red[tid] = acc;
    __syncthreads();
    if (tid < 64)
        atomicAdd(&psum[(g << 6) + e], red[e] + red[64 + e] + red[128 + e] + red[192 + e]);
}

// ----------- per-group: stable sort by top1 prob, rank, emit outputs ---------
__global__ __launch_bounds__(1024) void krouter(const float* __restrict__ g0,
                                                const float* __restrict__ g1,
                                                const int* __restrict__ i0,
                                                const int* __restrict__ i1,
                                                const int* __restrict__ capPtr,
                                                float* __restrict__ outDisp,
                                                float* __restrict__ outComb) {
    const int g = blockIdx.x, tid = threadIdx.x;
    __shared__ unsigned long long sk[NT];            // 32 KB sort keys
    __shared__ __align__(16) unsigned char seq[2 * NT];  // 8 KB expert sequence
    __shared__ unsigned short rank[2 * NT];          // 16 KB local ranks
    __shared__ int hist[16][64];                     // 4 KB chunk histograms

    const float* g0g = g0 + (g << 12);
    const float* g1g = g1 + (g << 12);
    const int* i0g = i0 + (g << 12);
    const int* i1g = i1 + (g << 12);

    // keys: descending top1-prob, ties -> ascending token (== stable argsort(-gate))
    for (int s = tid; s < NT; s += 1024) {
        const unsigned int pb = __float_as_uint(g0g[s]);   // prob > 0 -> orderable bits
        sk[s] = ((unsigned long long)(~pb) << 32) | (unsigned int)s;
    }
    __syncthreads();

    // bitonic sort ascending, n = 4096
    for (int k = 2; k <= NT; k <<= 1) {
        for (int j = k >> 1; j > 0; j >>= 1) {
            for (int i = tid; i < NT; i += 1024) {
                const int l = i ^ j;
                if (l > i) {
                    const unsigned long long a = sk[i], b = sk[l];
                    const bool up = ((i & k) == 0);
                    if ((a > b) == up) { sk[i] = b; sk[l] = a; }
                }
            }
            __syncthreads();
        }
    }

    // expert sequence: slot0 of sorted tokens, then slot1
    for (int s = tid; s < NT; s += 1024) {
        const int tok = (int)(sk[s] & 0xFFFFu);
        seq[s] = (unsigned char)i0g[tok];
        seq[NT + s] = (unsigned char)i1g[tok];
    }
    __syncthreads();

    // chunked per-expert running rank: 16 waves x 512 items, lane == expert
    const int wave = tid >> 6, lane = tid & 63;
    const int base = wave << 9;
    int cnt = 0;
    const unsigned long long* sp8 = (const unsigned long long*)(seq + base);
    for (int i = 0; i < 64; ++i) {
        const unsigned long long v = sp8[i];
#pragma unroll
        for (int b = 0; b < 8; ++b) {
            const int ex = (int)((v >> (8 * b)) & 0xFFu);
            const bool mt = (ex == lane);
            if (mt) rank[base + i * 8 + b] = (unsigned short)cnt;
            cnt += mt ? 1 : 0;
        }
    }
    hist[wave][lane] = cnt;
    __syncthreads();
    if (tid < 64) {   // exclusive scan over chunks per expert
        int off = 0;
#pragma unroll
        for (int w = 0; w < 16; ++w) { const int c = hist[w][tid]; hist[w][tid] = off; off += c; }
    }
    __syncthreads();

    const int cap = capPtr[0];
    for (int s = tid; s < 2 * NT; s += 1024) {
        const int slot = s >> 12;
        const int sp = s & (NT - 1);
        const int tok = (int)(sk[sp] & 0xFFFFu);
        const int e = seq[s];
        const int pri = (int)rank[s] + hist[s >> 9][e];
        const float gate = slot ? g1g[tok] : g0g[tok];
        const float cw = (pri < cap) ? gate : 0.0f;
        const size_t ob = (((size_t)(g << 12) + tok) * 2 + slot) * 2;
        outDisp[ob] = (float)e;
        outDisp[ob + 1] = (float)pri;
        outComb[((size_t)(g << 12) + tok) * 2 + slot] = cw;
    }
}

// ------------------------------ scalar losses --------------------------------
__global__ __launch_bounds__(512) void kfinal(const int* __restrict__ gcnt,
                                              const float* __restrict__ psum,
                                              const float* __restrict__ zacc,
                                              float* __restrict__ outAux,
                                              float* __restrict__ outZ) {
    __shared__ float red[512];
    const int tid = threadIdx.x;
    red[tid] = (float)gcnt[tid] * psum[tid];
    __syncthreads();
    for (int st = 256; st > 0; st >>= 1) {
        if (tid < st) red[tid] += red[tid + st];
        __syncthreads();
    }
    if (tid == 0) {
        *outAux = red[0] * ((float)NE / ((float)NG * (float)NT * (float)NT));
        *outZ = zacc[0] * (1.0f / (float)NTOK);
    }
}

extern "C" void kernel_launch(void* const* d_in, const int* in_sizes, int n_in,
                              void* d_out, int out_size, void* d_ws, size_t ws_size,
                              hipStream_t stream) {
    const float* A = (const float*)d_in[0];
    const float* W = (const float*)d_in[1];
    const float* bias = (const float*)d_in[2];
    const int* cap = (const int*)d_in[3];

    float* out = (float*)d_out;
    float* outDisp = out;                    // 131072
    float* outComb = out + 131072;           // 65536
    float* outAux = out + 196608;            // 1
    float* probs = out + 196609;             // 2097152 (logits then probs)
    float* outZ = out + 2293761;             // 1

    float* wsf = (float*)d_ws;
    int* gcnt = (int*)d_ws;                  // 512 ints
    float* psum = wsf + 512;                 // 512 floats
    float* zacc = wsf + 1024;                // 1 float
    float* g0 = wsf + 1088;                  // 32768
    float* g1 = wsf + 1088 + 32768;          // 32768
    int* i0 = (int*)d_ws + 1088 + 65536;     // 32768
    int* i1 = (int*)d_ws + 1088 + 98304;     // 32768

    hipMemsetAsync(d_ws, 0, 4100, stream);   // zero gcnt, psum, zacc

    kgemm<<<NTOK / 64, 256, 0, stream>>>(A, W, bias, probs);
    ksoftmax<<<NTOK / 256, 256, 0, stream>>>(probs, g0, g1, i0, i1, gcnt, zacc);
    kpsum<<<NG * 64, 256, 0, stream>>>(probs, psum);
    krouter<<<NG, 1024, 0, stream>>>(g0, g1, i0, i1, cap, outDisp, outComb);
    kfinal<<<1, 512, 0, stream>>>(gcnt, psum, zacc, outAux, outZ);
}